// Round 6
// baseline (195.999 us; speedup 1.0000x reference)
//
#include <hip/hip_runtime.h>

typedef unsigned short u16;
typedef __bf16 bf16x8 __attribute__((ext_vector_type(8)));
typedef float f32x16 __attribute__((ext_vector_type(16)));

union B8 { bf16x8 v; u16 s[8]; unsigned u[4]; uint4 u4; };

__device__ __forceinline__ unsigned cvtpk(float a, float b) {
    unsigned r;
    asm("v_cvt_pk_bf16_f32 %0, %1, %2" : "=v"(r) : "v"(a), "v"(b));
    return r;
}
__device__ __forceinline__ float ex2(float x) { return __builtin_amdgcn_exp2f(x); }
__device__ __forceinline__ void swap32(unsigned &a, unsigned &b) {
    asm("v_permlane32_swap_b32 %0, %1" : "+v"(a), "+v"(b));
}
__device__ __forceinline__ B8 load_w8(const float* __restrict__ p, float s) {
    float4 lo = ((const float4*)p)[0];
    float4 hi = ((const float4*)p)[1];
    B8 r;
    r.u[0] = cvtpk(lo.x * s, lo.y * s);
    r.u[1] = cvtpk(lo.z * s, lo.w * s);
    r.u[2] = cvtpk(hi.x * s, hi.y * s);
    r.u[3] = cvtpk(hi.z * s, hi.w * s);
    return r;
}
__device__ __forceinline__ f32x16 mfma32(const B8 a, const B8 b, f32x16 c) {
    return __builtin_amdgcn_mfma_f32_32x32x16_bf16(a.v, b.v, c, 0, 0, 0);
}
// K LDS: [512 tok][32 ck] u16, 4x16B slots per row XOR-swizzled by (tok>>1)&3
__device__ __forceinline__ int kidx(int row, int sl) {
    return row * 32 + (((sl ^ (row >> 1)) & 3) << 3);
}
// V LDS: [64 cv][264 u16], 256-tok region = 32 slots of 8 u16, slot ^= ((cv^(cv>>3))&3)
#define SWZV(cv) (((cv) ^ ((cv) >> 3)) & 3)
// D-regs (rows (r&3)+8*(r>>2)+4*h5) -> two B-fragments (k-chunks of 16) via cvtpk+permlane
__device__ __forceinline__ void build_b(const float* p, B8& b0, B8& b1) {
    unsigned c0 = cvtpk(p[0], p[1]),   c1 = cvtpk(p[2], p[3]);
    unsigned c2 = cvtpk(p[4], p[5]),   c3 = cvtpk(p[6], p[7]);
    unsigned c4 = cvtpk(p[8], p[9]),   c5 = cvtpk(p[10], p[11]);
    unsigned c6 = cvtpk(p[12], p[13]), c7 = cvtpk(p[14], p[15]);
    swap32(c0, c2); swap32(c1, c3); swap32(c4, c6); swap32(c5, c7);
    b0.u[0] = c0; b0.u[1] = c1; b0.u[2] = c2; b0.u[3] = c3;
    b1.u[0] = c4; b1.u[1] = c5; b1.u[2] = c6; b1.u[3] = c7;
}

// LDS: K [512][32] swz @0 (32768B) | V [64][264] swz @32768 (33792B) => 66560B
// epilogue overlay: 8 wave-slots of [64 co][36 q-pad] f32 (9216B) = 73728B total
#define VOFF 16384          // u16 index
#define NSM  36864          // u16 count = 73728 B

__global__ __launch_bounds__(512, 4)
void psab_fused(const float* __restrict__ x,
                const float* __restrict__ wk, const float* __restrict__ bk,
                const float* __restrict__ wv, const float* __restrict__ bv,
                const float* __restrict__ wo, const float* __restrict__ bo,
                float* __restrict__ out)
{
    __shared__ __align__(16) u16 smem[NSM];
    const int t    = threadIdx.x;
    const int lane = t & 63;
    const int wid  = t >> 6;        // 8 waves
    const int cl   = lane & 31;
    const int h5   = lane >> 5;

    // window n + q-half qh; pair (n,0),(n,1) lands on the same XCD (assumes xcd = bid%8)
    const int bid = blockIdx.x;
    const int xcd = bid & 7;
    const int ii  = bid >> 3;            // 0..127
    const int n   = xcd * 64 + (ii >> 1);
    const int qh  = ii & 1;
    const int sh = n >> 6, sw = (n >> 3) & 7, sd = n & 7;
    const size_t base_vox = (size_t)(sh * 8) * 4096 + (size_t)(sw * 8) * 64 + (size_t)(sd * 8);
    const float* xb = x + base_vox;

    const float WSC = 0.50506330f;   // sqrt(log2(e)/sqrt(32)) folded into K weights
    const f32x16 z16 = {0,0,0,0,0,0,0,0,0,0,0,0,0,0,0,0};

    // ---- x fragment gather: group G = 32 tokens; same regs serve K-proj B and V-proj A ----
    B8 ax[4];
#define GATHER(G)                                                                             \
    {                                                                                         \
        const int vox = ((G) >> 1) * 4096 + (((G) & 1) * 4 + (cl >> 3)) * 64 + (cl & 7);      \
        const float* px = xb + vox;                                                           \
        _Pragma("unroll")                                                                     \
        for (int kc = 0; kc < 4; ++kc) {                                                      \
            float f0 = px[(size_t)(kc * 16 + h5 * 8 + 0) * 262144];                           \
            float f1 = px[(size_t)(kc * 16 + h5 * 8 + 1) * 262144];                           \
            float f2 = px[(size_t)(kc * 16 + h5 * 8 + 2) * 262144];                           \
            float f3 = px[(size_t)(kc * 16 + h5 * 8 + 3) * 262144];                           \
            float f4 = px[(size_t)(kc * 16 + h5 * 8 + 4) * 262144];                           \
            float f5 = px[(size_t)(kc * 16 + h5 * 8 + 5) * 262144];                           \
            float f6 = px[(size_t)(kc * 16 + h5 * 8 + 6) * 262144];                           \
            float f7 = px[(size_t)(kc * 16 + h5 * 8 + 7) * 262144];                           \
            ax[kc].u[0] = cvtpk(f0, f1); ax[kc].u[1] = cvtpk(f2, f3);                         \
            ax[kc].u[2] = cvtpk(f4, f5); ax[kc].u[3] = cvtpk(f6, f7);                         \
        }                                                                                     \
    }

#define VPROJ(TOKL)                                                                           \
    _Pragma("unroll")                                                                         \
    for (int nb = 0; nb < 2; ++nb) {                                                          \
        f32x16 vd = mfma32(ax[0], wvB[nb][0], z16);                                           \
        vd = mfma32(ax[1], wvB[nb][1], vd);                                                   \
        vd = mfma32(ax[2], wvB[nb][2], vd);                                                   \
        vd = mfma32(ax[3], wvB[nb][3], vd);                                                   \
        const int cv = nb * 32 + cl;                                                          \
        const float vb = nb ? vb1 : vb0;                                                      \
        const int swv = SWZV(cv);                                                             \
        _Pragma("unroll")                                                                     \
        for (int rq = 0; rq < 4; ++rq) {                                                      \
            uint2 pk;                                                                         \
            pk.x = cvtpk(vd[rq * 4 + 0] + vb, vd[rq * 4 + 1] + vb);                           \
            pk.y = cvtpk(vd[rq * 4 + 2] + vb, vd[rq * 4 + 3] + vb);                           \
            const int off = (TOKL) + rq * 8 + 4 * h5;                                         \
            *(uint2*)&smem[VOFF + cv * 264 + (((off >> 3) ^ swv) << 3) + (off & 7)] = pk;     \
        }                                                                                     \
    }

    // ---- phase 1: proj K (all waves, own 64 tok) + V half-A (waves 0-3) ----
    {
        B8 wkA[4];
#pragma unroll
        for (int kc = 0; kc < 4; ++kc)
            wkA[kc] = load_w8(wk + cl * 64 + kc * 16 + h5 * 8, WSC);
        float bkv[16];
#pragma unroll
        for (int r = 0; r < 16; ++r)
            bkv[r] = bk[(r & 3) + 8 * (r >> 2) + 4 * h5] * WSC;
        B8 wvB[2][4];
        float vb0 = 0.f, vb1 = 0.f;
        if (wid < 4) {
#pragma unroll
            for (int nb = 0; nb < 2; ++nb)
#pragma unroll
                for (int kc = 0; kc < 4; ++kc)
                    wvB[nb][kc] = load_w8(wv + (nb * 32 + cl) * 64 + kc * 16 + h5 * 8, 1.0f);
            vb0 = bv[cl]; vb1 = bv[32 + cl];
        }
#pragma unroll
        for (int sb = 0; sb < 2; ++sb) {
            const int g = wid * 2 + sb;          // token group 0..15
            GATHER(g)
            // K proj swapped (W as A): D col = tok, rows = ck
            f32x16 kd = mfma32(wkA[0], ax[0], z16);
            kd = mfma32(wkA[1], ax[1], kd);
            kd = mfma32(wkA[2], ax[2], kd);
            kd = mfma32(wkA[3], ax[3], kd);
            const int trow = g * 32 + cl;
#pragma unroll
            for (int g2 = 0; g2 < 4; ++g2) {
                uint2 pk;
                pk.x = cvtpk(kd[4 * g2 + 0] + bkv[4 * g2 + 0], kd[4 * g2 + 1] + bkv[4 * g2 + 1]);
                pk.y = cvtpk(kd[4 * g2 + 2] + bkv[4 * g2 + 2], kd[4 * g2 + 3] + bkv[4 * g2 + 3]);
                *(uint2*)&smem[kidx(trow, g2) + 4 * h5] = pk;
            }
            if (wid < 4) { VPROJ(g * 32) }
        }
    }
    __syncthreads();                          // (1) K full + V half-A ready

    // ---- attention: wave owns q = qh*256 + wid*32 + cl ----
    B8 qB[2];
#pragma unroll
    for (int kc = 0; kc < 2; ++kc)
        qB[kc].u4 = *(const uint4*)&smem[kidx(qh * 256 + wid * 32 + cl, 2 * kc + h5)];

    f32x16 ctx0 = z16, ctx1 = z16;
    float lsum = 0.f;

#define ATTN_PASS(CI0, CI1, MOFF)                                                             \
    _Pragma("unroll 2")                                                                       \
    for (int ci = (CI0); ci < (CI1); ++ci) {                                                  \
        const int m0 = ci * 32;                                                               \
        const int s0i = ((m0 - (MOFF)) >> 3) + h5;                                            \
        B8 kA0, kA1, va00, va01, va10, va11;                                                  \
        kA0.u4  = *(const uint4*)&smem[kidx(m0 + cl, h5)];                                    \
        kA1.u4  = *(const uint4*)&smem[kidx(m0 + cl, 2 + h5)];                                \
        va00.u4 = *(const uint4*)&smem[VOFF + cl * 264 + ((s0i ^ SWZV(cl)) << 3)];            \
        va01.u4 = *(const uint4*)&smem[VOFF + cl * 264 + (((s0i + 2) ^ SWZV(cl)) << 3)];      \
        va10.u4 = *(const uint4*)&smem[VOFF + (32 + cl) * 264 + ((s0i ^ SWZV(32 + cl)) << 3)];\
        va11.u4 = *(const uint4*)&smem[VOFF + (32 + cl) * 264 + (((s0i + 2) ^ SWZV(32 + cl)) << 3)]; \
        f32x16 s = mfma32(kA0, qB[0], z16);                                                   \
        s = mfma32(kA1, qB[1], s);                                                            \
        float p[16];                                                                          \
        _Pragma("unroll")                                                                     \
        for (int i2 = 0; i2 < 16; ++i2) p[i2] = ex2(s[i2]);                                   \
        lsum += (((p[0]+p[1])+(p[2]+p[3]))+((p[4]+p[5])+(p[6]+p[7])))                         \
              + (((p[8]+p[9])+(p[10]+p[11]))+((p[12]+p[13])+(p[14]+p[15])));                  \
        B8 pb0, pb1;                                                                          \
        build_b(p, pb0, pb1);                                                                 \
        ctx0 = mfma32(va00, pb0, ctx0);                                                       \
        ctx0 = mfma32(va01, pb1, ctx0);                                                       \
        ctx1 = mfma32(va10, pb0, ctx1);                                                       \
        ctx1 = mfma32(va11, pb1, ctx1);                                                       \
    }

    ATTN_PASS(0, 8, 0)
    __syncthreads();                          // (2) half-A reads done

    if (wid >= 4) {                           // ---- phase 3: V half-B (waves 4-7) ----
        B8 wvB[2][4];
#pragma unroll
        for (int nb = 0; nb < 2; ++nb)
#pragma unroll
            for (int kc = 0; kc < 4; ++kc)
                wvB[nb][kc] = load_w8(wv + (nb * 32 + cl) * 64 + kc * 16 + h5 * 8, 1.0f);
        const float vb0 = bv[cl], vb1 = bv[32 + cl];
#pragma unroll
        for (int sb = 0; sb < 2; ++sb) {
            const int g = wid * 2 + sb;       // 8..15
            GATHER(g)
            VPROJ(g * 32 - 256)
        }
    }
    __syncthreads();                          // (3) half-B ready

    ATTN_PASS(8, 16, 256)

    lsum += __shfl_xor(lsum, 32);
    const float inv = 1.0f / lsum;

    // out-proj A-frags + ctx -> B-frags
    B8 aw[2][4];
#pragma unroll
    for (int cob = 0; cob < 2; ++cob)
#pragma unroll
        for (int kc = 0; kc < 4; ++kc)
            aw[cob][kc] = load_w8(wo + (cob * 32 + cl) * 64 + kc * 16 + h5 * 8, 1.0f);
    float pn[16];
    B8 cq[4];
#pragma unroll
    for (int i = 0; i < 16; ++i) pn[i] = ctx0[i] * inv;
    build_b(pn, cq[0], cq[1]);
#pragma unroll
    for (int i = 0; i < 16; ++i) pn[i] = ctx1[i] * inv;
    build_b(pn, cq[2], cq[3]);

    __syncthreads();                          // (4) all K/V reads done; fout overlay safe

    float* fout = (float*)((char*)smem + wid * 9216);   // [64 co][36 pad] f32
#pragma unroll
    for (int cob = 0; cob < 2; ++cob) {
        f32x16 od = mfma32(aw[cob][0], cq[0], z16);
        od = mfma32(aw[cob][1], cq[1], od);
        od = mfma32(aw[cob][2], cq[2], od);
        od = mfma32(aw[cob][3], cq[3], od);
#pragma unroll
        for (int r = 0; r < 16; ++r) {
            const int row = cob * 32 + (r & 3) + 8 * (r >> 2) + 4 * h5;
            fout[row * 36 + cl] = od[r];
        }
    }

    // global store: hb = qh*4 + wid>>1, half-row sb = wid&1
    const int hb = qh * 4 + (wid >> 1);
    const int sb = wid & 1;
    float* outw = out + base_vox + (size_t)hb * 4096 + sb * 4 * 64;
    const int q4 = (lane & 7) * 4;
    const int wb = q4 >> 3, db0 = q4 & 7;
#pragma unroll
    for (int it = 0; it < 8; ++it) {
        const int co = it * 8 + (lane >> 3);
        float4 v4 = *(const float4*)&fout[co * 36 + q4];
        const float bco = bo[co];
        v4.x += bco; v4.y += bco; v4.z += bco; v4.w += bco;
        *(float4*)&outw[(size_t)co * 262144 + wb * 64 + db0] = v4;
    }
}

extern "C" void kernel_launch(void* const* d_in, const int* in_sizes, int n_in,
                              void* d_out, int out_size, void* d_ws, size_t ws_size,
                              hipStream_t stream) {
    const float* x  = (const float*)d_in[0];
    const float* wk = (const float*)d_in[1];
    const float* bk = (const float*)d_in[2];
    const float* wv = (const float*)d_in[3];
    const float* bv = (const float*)d_in[4];
    const float* wo = (const float*)d_in[5];
    const float* bo = (const float*)d_in[6];
    float* o = (float*)d_out;
    psab_fused<<<dim3(1024), dim3(512), 0, stream>>>(x, wk, bk, wv, bv, wo, bo, o);
}